// Round 3
// baseline (659.941 us; speedup 1.0000x reference)
//
#include <hip/hip_runtime.h>
#include <math.h>

#define C_DIM 128
#define KNN 8
#define NPTS 8192
#define M_TOTAL 16384   // B*N
#define CHUNK 1024      // points staged in LDS per iteration of the KNN scan

// ---------------------------------------------------------------------------
// Kernel 1: coords -> packed float4 {x, y, z, |p|^2} per point
// ---------------------------------------------------------------------------
__global__ __launch_bounds__(256) void prep_coords(
    const float* __restrict__ coords, float4* __restrict__ c4) {
  int g = blockIdx.x * 256 + threadIdx.x;
  if (g < M_TOTAL) {
    float x = coords[3 * g + 0];
    float y = coords[3 * g + 1];
    float z = coords[3 * g + 2];
    // same fma ordering as the scan's dot product so self-distance cancels
    // to exactly 0.0f
    float s = fmaf(x, x, fmaf(y, y, z * z));
    c4[g] = make_float4(x, y, z, s);
  }
}

// ---------------------------------------------------------------------------
// Kernel 2: transpose the four 128x128 weight matrices once:
// WT[c][o] = W[o][c]. 256 blocks x 256 threads = 65536 = 4*128*128 elements.
// ---------------------------------------------------------------------------
__global__ __launch_bounds__(256) void transpose_w(
    const float* __restrict__ Wq, const float* __restrict__ Wk,
    const float* __restrict__ Wv, const float* __restrict__ Wo,
    float* __restrict__ Tq, float* __restrict__ Tk,
    float* __restrict__ Tv, float* __restrict__ To) {
  int g = blockIdx.x * 256 + threadIdx.x;
  int mat = g >> 14;          // 0..3
  int j = g & 16383;          // dest linear index: j = c*128 + o
  int c = j >> 7, o = j & 127;
  const float* src = (mat == 0) ? Wq : (mat == 1) ? Wk : (mat == 2) ? Wv : Wo;
  float* dst = (mat == 0) ? Tq : (mat == 1) ? Tk : (mat == 2) ? Tv : To;
  dst[j] = src[o * C_DIM + c];   // coalesced write, strided (L2-hit) read
}

// ---------------------------------------------------------------------------
// Kernel 3: Y = X @ W^T given WT[c][o] (pre-transposed, read via L1/L2).
// 64 rows per block, 256 threads, 4x8 register tile. LDS: 33 KB (X tile only).
// ---------------------------------------------------------------------------
__global__ __launch_bounds__(256) void gemm_xwt(
    const float* __restrict__ X, const float* __restrict__ WT,
    float* __restrict__ Y) {
  __shared__ float Xs[64][132];        // padded stride: conflict-free b128 reads

  const int t = threadIdx.x;
  const int row0 = blockIdx.x * 64;

  const float4* X4 = (const float4*)(X + (size_t)row0 * C_DIM);
  for (int i = t; i < 64 * 32; i += 256) {
    int r = i >> 5, c4 = i & 31;
    float4 vv = X4[i];
    *(float4*)&Xs[r][c4 * 4] = vv;
  }
  __syncthreads();

  const int tx = t & 15;        // 16 column groups of 8 outputs
  const int ty = t >> 4;        // 16 row groups of 4 rows
  const int r0 = ty * 4;
  const int o0 = tx * 8;

  float acc[4][8];
#pragma unroll
  for (int i = 0; i < 4; ++i)
#pragma unroll
    for (int j = 0; j < 8; ++j) acc[i][j] = 0.0f;

  for (int c = 0; c < C_DIM; c += 4) {
    float xs[4][4];
#pragma unroll
    for (int i = 0; i < 4; ++i) {
      float4 xv = *(const float4*)&Xs[r0 + i][c];
      xs[i][0] = xv.x; xs[i][1] = xv.y; xs[i][2] = xv.z; xs[i][3] = xv.w;
    }
#pragma unroll
    for (int cc = 0; cc < 4; ++cc) {
      float4 wa = *(const float4*)&WT[(size_t)(c + cc) * C_DIM + o0];
      float4 wb = *(const float4*)&WT[(size_t)(c + cc) * C_DIM + o0 + 4];
#pragma unroll
      for (int i = 0; i < 4; ++i) {
        float x = xs[i][cc];
        acc[i][0] = fmaf(x, wa.x, acc[i][0]);
        acc[i][1] = fmaf(x, wa.y, acc[i][1]);
        acc[i][2] = fmaf(x, wa.z, acc[i][2]);
        acc[i][3] = fmaf(x, wa.w, acc[i][3]);
        acc[i][4] = fmaf(x, wb.x, acc[i][4]);
        acc[i][5] = fmaf(x, wb.y, acc[i][5]);
        acc[i][6] = fmaf(x, wb.z, acc[i][6]);
        acc[i][7] = fmaf(x, wb.w, acc[i][7]);
      }
    }
  }

#pragma unroll
  for (int i = 0; i < 4; ++i) {
    float* yrow = Y + (size_t)(row0 + r0 + i) * C_DIM + o0;
    *(float4*)yrow = make_float4(acc[i][0], acc[i][1], acc[i][2], acc[i][3]);
    *(float4*)(yrow + 4) = make_float4(acc[i][4], acc[i][5], acc[i][6], acc[i][7]);
  }
}

// ---------------------------------------------------------------------------
// Kernel 4: fused KNN (top-8 by clamped d2, lex (d2, idx) tie-break) + attn.
// One wave per query, 4 waves/block; coords chunk-staged in LDS (16 KB).
// ---------------------------------------------------------------------------
__global__ __launch_bounds__(256) void knn_attn(
    const float4* __restrict__ c4,
    const float* __restrict__ q, const float* __restrict__ k,
    const float* __restrict__ v, const float* __restrict__ log_gamma_p,
    float* __restrict__ agg) {
  __shared__ float4 pts[CHUNK];   // 16 KB

  const int t = threadIdx.x;
  const int wave = t >> 6;
  const int lane = t & 63;
  const int qi = blockIdx.x * 4 + wave;          // 0..16383; blocks never
  const int b = qi >> 13;                        // straddle a batch boundary
  const int n = qi & (NPTS - 1);
  const int base = b * NPTS;

  const float4 qp = c4[base + n];   // {x,y,z,|p|^2}

  // lane-local sorted top-8, ascending lex (d2, idx); static indexing only
  float bd[KNN]; int bi[KNN];
#pragma unroll
  for (int j = 0; j < KNN; ++j) { bd[j] = INFINITY; bi[j] = 0x7fffffff; }

  for (int ch = 0; ch < NPTS / CHUNK; ++ch) {
    __syncthreads();   // previous chunk fully consumed
    for (int i = t; i < CHUNK; i += 256) pts[i] = c4[base + ch * CHUNK + i];
    __syncthreads();

#pragma unroll 4
    for (int it = 0; it < CHUNK / 64; ++it) {
      const int ml = it * 64 + lane;
      const float4 pm = pts[ml];
      const int m = ch * CHUNK + ml;
      float dot = fmaf(qp.x, pm.x, fmaf(qp.y, pm.y, qp.z * pm.z));
      float d2 = qp.w + pm.w - 2.0f * dot;
      d2 = fmaxf(d2, 0.0f);
      if (d2 < bd[KNN - 1] || (d2 == bd[KNN - 1] && m < bi[KNN - 1])) {
        bd[KNN - 1] = d2; bi[KNN - 1] = m;
#pragma unroll
        for (int j = KNN - 1; j > 0; --j) {
          bool sw = (bd[j] < bd[j - 1]) ||
                    (bd[j] == bd[j - 1] && bi[j] < bi[j - 1]);
          if (sw) {
            float td = bd[j]; bd[j] = bd[j - 1]; bd[j - 1] = td;
            int ti = bi[j]; bi[j] = bi[j - 1]; bi[j - 1] = ti;
          }
        }
      }
    }
  }

  // wave merge: 8 rounds of butterfly lex-min over (d2, idx)
  int ni_[KNN];
#pragma unroll
  for (int r = 0; r < KNN; ++r) {
    float cd = bd[0]; int ci = bi[0];
#pragma unroll
    for (int off = 32; off > 0; off >>= 1) {
      float od = __shfl_xor(cd, off, 64);
      int oi = __shfl_xor(ci, off, 64);
      if (od < cd || (od == cd && oi < ci)) { cd = od; ci = oi; }
    }
    ni_[r] = ci;
    if (ci == bi[0]) {   // unique owner pops its head
#pragma unroll
      for (int j = 0; j < KNN - 1; ++j) { bd[j] = bd[j + 1]; bi[j] = bi[j + 1]; }
      bd[KNN - 1] = INFINITY; bi[KNN - 1] = 0x7fffffff;
    }
  }

  // ---- attention over the 8 neighbors (output is order-invariant) ----
  const float lg = *log_gamma_p;
  const size_t qrow = (size_t)(base + n) * C_DIM;
  const float qv0 = q[qrow + lane];
  const float qv1 = q[qrow + lane + 64];

  float score[KNN];
#pragma unroll
  for (int j = 0; j < KNN; ++j) {
    const int mj = ni_[j];
    const size_t krow = (size_t)(base + mj) * C_DIM;
    float p = fmaf(qv1, k[krow + lane + 64], qv0 * k[krow + lane]);
#pragma unroll
    for (int off = 32; off > 0; off >>= 1) p += __shfl_xor(p, off, 64);
    // gamma from the diff-based safe norm (reference's second formula)
    const float4 pm = c4[base + mj];
    float dx = qp.x - pm.x, dy = qp.y - pm.y, dz = qp.z - pm.z;
    float d2p = fmaf(dx, dx, fmaf(dy, dy, dz * dz));
    float dist = d2p > 0.0f ? sqrtf(d2p) : 0.0f;
    float gw = expf(lg * dist);
    score[j] = (p / 11.313708498984761f) * gw;   // /sqrt(128) then *gamma
  }

  float mx = score[0];
#pragma unroll
  for (int j = 1; j < KNN; ++j) mx = fmaxf(mx, score[j]);
  float w[KNN]; float sum = 0.0f;
#pragma unroll
  for (int j = 0; j < KNN; ++j) { w[j] = expf(score[j] - mx); sum += w[j]; }
#pragma unroll
  for (int j = 0; j < KNN; ++j) w[j] = w[j] / sum;

  float a0 = 0.0f, a1 = 0.0f;
#pragma unroll
  for (int j = 0; j < KNN; ++j) {
    const size_t vrow = (size_t)(base + ni_[j]) * C_DIM;
    a0 = fmaf(w[j], v[vrow + lane], a0);
    a1 = fmaf(w[j], v[vrow + lane + 64], a1);
  }
  // agg aliases q's storage: safe, each q row is read only by its own wave
  agg[qrow + lane] = a0;
  agg[qrow + lane + 64] = a1;
}

// ---------------------------------------------------------------------------
extern "C" void kernel_launch(void* const* d_in, const int* in_sizes, int n_in,
                              void* d_out, int out_size, void* d_ws, size_t ws_size,
                              hipStream_t stream) {
  const float* feats  = (const float*)d_in[0];
  const float* coords = (const float*)d_in[1];
  const float* Wq     = (const float*)d_in[2];
  const float* Wk     = (const float*)d_in[3];
  const float* Wv     = (const float*)d_in[4];
  const float* Wo     = (const float*)d_in[5];
  const float* lg     = (const float*)d_in[6];
  float* out = (float*)d_out;

  float* ws = (float*)d_ws;
  const size_t ROWS = (size_t)M_TOTAL * C_DIM;   // 2,097,152 floats
  float*  q   = ws;                               // 8 MB
  float*  k   = ws + ROWS;                        // 8 MB
  float*  v   = ws + 2 * ROWS;                    // 8 MB
  float4* c4  = (float4*)(ws + 3 * ROWS);         // 256 KB, 16B-aligned
  float*  WTq = ws + 3 * ROWS + 4 * (size_t)M_TOTAL;
  float*  WTk = WTq + C_DIM * C_DIM;
  float*  WTv = WTk + C_DIM * C_DIM;
  float*  WTo = WTv + C_DIM * C_DIM;              // total ws use: ~24.8 MB
  float*  agg = q;                                // reuse q's buffer

  prep_coords<<<M_TOTAL / 256, 256, 0, stream>>>(coords, c4);
  transpose_w<<<256, 256, 0, stream>>>(Wq, Wk, Wv, Wo, WTq, WTk, WTv, WTo);
  gemm_xwt<<<M_TOTAL / 64, 256, 0, stream>>>(feats, WTq, q);
  gemm_xwt<<<M_TOTAL / 64, 256, 0, stream>>>(feats, WTk, k);
  gemm_xwt<<<M_TOTAL / 64, 256, 0, stream>>>(feats, WTv, v);
  knn_attn<<<M_TOTAL / 4, 256, 0, stream>>>(c4, q, k, v, lg, agg);
  // NOTE: must pass the pre-transposed WTo here (round-2 bug: passed Wo)
  gemm_xwt<<<M_TOTAL / 64, 256, 0, stream>>>(agg, WTo, out);
}

// Round 4
// 362.021 us; speedup vs baseline: 1.8229x; 1.8229x over previous
//
#include <hip/hip_runtime.h>
#include <math.h>

#define C_DIM 128
#define KNN 8
#define NPTS 8192
#define M_TOTAL 16384   // B*N
#define CHUNK 1024      // points staged in LDS per iteration of the KNN scan

// ---------------------------------------------------------------------------
// Kernel 1: coords -> packed float4 {x, y, z, |p|^2} per point
// ---------------------------------------------------------------------------
__global__ __launch_bounds__(256) void prep_coords(
    const float* __restrict__ coords, float4* __restrict__ c4) {
  int g = blockIdx.x * 256 + threadIdx.x;
  if (g < M_TOTAL) {
    float x = coords[3 * g + 0];
    float y = coords[3 * g + 1];
    float z = coords[3 * g + 2];
    // same fma ordering as the scan's dot product so self-distance cancels
    // to exactly 0.0f
    float s = fmaf(x, x, fmaf(y, y, z * z));
    c4[g] = make_float4(x, y, z, s);
  }
}

// ---------------------------------------------------------------------------
// Kernel 2: transpose the four 128x128 weight matrices once: WT[c][o]=W[o][c]
// ---------------------------------------------------------------------------
__global__ __launch_bounds__(256) void transpose_w(
    const float* __restrict__ Wq, const float* __restrict__ Wk,
    const float* __restrict__ Wv, const float* __restrict__ Wo,
    float* __restrict__ Tq, float* __restrict__ Tk,
    float* __restrict__ Tv, float* __restrict__ To) {
  int g = blockIdx.x * 256 + threadIdx.x;
  int mat = g >> 14;          // 0..3
  int j = g & 16383;          // dest linear index: j = c*128 + o
  int c = j >> 7, o = j & 127;
  const float* src = (mat == 0) ? Wq : (mat == 1) ? Wk : (mat == 2) ? Wv : Wo;
  float* dst = (mat == 0) ? Tq : (mat == 1) ? Tk : (mat == 2) ? Tv : To;
  dst[j] = src[o * C_DIM + c];   // coalesced write, strided (L2-hit) read
}

// ---------------------------------------------------------------------------
// GEMM body: one 64-row X tile (already staged in Xs) times one WT -> Y.
// ---------------------------------------------------------------------------
__device__ __forceinline__ void gemm_tile(
    const float (*Xs)[132], const float* __restrict__ WT,
    float* __restrict__ Y, int row0, int r0, int o0) {
  float acc[4][8];
#pragma unroll
  for (int i = 0; i < 4; ++i)
#pragma unroll
    for (int j = 0; j < 8; ++j) acc[i][j] = 0.0f;

  for (int c = 0; c < C_DIM; c += 4) {
    float xs[4][4];
#pragma unroll
    for (int i = 0; i < 4; ++i) {
      float4 xv = *(const float4*)&Xs[r0 + i][c];
      xs[i][0] = xv.x; xs[i][1] = xv.y; xs[i][2] = xv.z; xs[i][3] = xv.w;
    }
#pragma unroll
    for (int cc = 0; cc < 4; ++cc) {
      float4 wa = *(const float4*)&WT[(size_t)(c + cc) * C_DIM + o0];
      float4 wb = *(const float4*)&WT[(size_t)(c + cc) * C_DIM + o0 + 4];
#pragma unroll
      for (int i = 0; i < 4; ++i) {
        float x = xs[i][cc];
        acc[i][0] = fmaf(x, wa.x, acc[i][0]);
        acc[i][1] = fmaf(x, wa.y, acc[i][1]);
        acc[i][2] = fmaf(x, wa.z, acc[i][2]);
        acc[i][3] = fmaf(x, wa.w, acc[i][3]);
        acc[i][4] = fmaf(x, wb.x, acc[i][4]);
        acc[i][5] = fmaf(x, wb.y, acc[i][5]);
        acc[i][6] = fmaf(x, wb.z, acc[i][6]);
        acc[i][7] = fmaf(x, wb.w, acc[i][7]);
      }
    }
  }

#pragma unroll
  for (int i = 0; i < 4; ++i) {
    float* yrow = Y + (size_t)(row0 + r0 + i) * C_DIM + o0;
    *(float4*)yrow = make_float4(acc[i][0], acc[i][1], acc[i][2], acc[i][3]);
    *(float4*)(yrow + 4) = make_float4(acc[i][4], acc[i][5], acc[i][6], acc[i][7]);
  }
}

// ---------------------------------------------------------------------------
// Kernel 3a: fused q/k/v projection — stage X tile once, apply 3 weights.
// ---------------------------------------------------------------------------
__global__ __launch_bounds__(256) void gemm_qkv(
    const float* __restrict__ X,
    const float* __restrict__ WTq, const float* __restrict__ WTk,
    const float* __restrict__ WTv,
    float* __restrict__ Yq, float* __restrict__ Yk, float* __restrict__ Yv) {
  __shared__ float Xs[64][132];
  const int t = threadIdx.x;
  const int row0 = blockIdx.x * 64;

  const float4* X4 = (const float4*)(X + (size_t)row0 * C_DIM);
  for (int i = t; i < 64 * 32; i += 256) {
    int r = i >> 5, c4i = i & 31;
    *(float4*)&Xs[r][c4i * 4] = X4[i];
  }
  __syncthreads();

  const int r0 = (t >> 4) * 4;
  const int o0 = (t & 15) * 8;
  gemm_tile(Xs, WTq, Yq, row0, r0, o0);
  gemm_tile(Xs, WTk, Yk, row0, r0, o0);
  gemm_tile(Xs, WTv, Yv, row0, r0, o0);
}

// ---------------------------------------------------------------------------
// Kernel 3b: single GEMM (output projection)
// ---------------------------------------------------------------------------
__global__ __launch_bounds__(256) void gemm_xwt(
    const float* __restrict__ X, const float* __restrict__ WT,
    float* __restrict__ Y) {
  __shared__ float Xs[64][132];
  const int t = threadIdx.x;
  const int row0 = blockIdx.x * 64;

  const float4* X4 = (const float4*)(X + (size_t)row0 * C_DIM);
  for (int i = t; i < 64 * 32; i += 256) {
    int r = i >> 5, c4i = i & 31;
    *(float4*)&Xs[r][c4i * 4] = X4[i];
  }
  __syncthreads();

  const int r0 = (t >> 4) * 4;
  const int o0 = (t & 15) * 8;
  gemm_tile(Xs, WT, Y, row0, r0, o0);
}

// ---------------------------------------------------------------------------
// Kernel 4: fused KNN + attention.
// Top-8 by u64 key = (bits(clamped d2) << 32) | idx  (lex (d2, idx) order,
// keys unique). tau-pruning: tau = wave-min of lane 8th-best, refreshed per
// chunk; skipping key >= tau is exact (global 8th-smallest <= tau).
// ---------------------------------------------------------------------------
__device__ __forceinline__ unsigned long long wave_min_u64(unsigned long long x) {
#pragma unroll
  for (int off = 32; off > 0; off >>= 1) {
    unsigned long long o = __shfl_xor(x, off, 64);
    x = (o < x) ? o : x;
  }
  return x;
}

__global__ __launch_bounds__(256) void knn_attn(
    const float4* __restrict__ c4,
    const float* __restrict__ q, const float* __restrict__ k,
    const float* __restrict__ v, const float* __restrict__ log_gamma_p,
    float* __restrict__ agg) {
  __shared__ float4 pts[CHUNK];   // 16 KB

  const int t = threadIdx.x;
  const int wave = t >> 6;
  const int lane = t & 63;
  const int qi = blockIdx.x * 4 + wave;          // blocks never straddle batch
  const int b = qi >> 13;
  const int n = qi & (NPTS - 1);
  const int base = b * NPTS;

  const float4 qp = c4[base + n];   // {x,y,z,|p|^2}

  // lane-local sorted top-8 of u64 keys, ascending; static indexing only
  unsigned long long kk[KNN];
#pragma unroll
  for (int j = 0; j < KNN; ++j) kk[j] = ~0ull;
  unsigned long long tau = ~0ull;

  for (int ch = 0; ch < NPTS / CHUNK; ++ch) {
    __syncthreads();   // previous chunk fully consumed
    for (int i = t; i < CHUNK; i += 256) pts[i] = c4[base + ch * CHUNK + i];
    __syncthreads();

#pragma unroll 4
    for (int it = 0; it < CHUNK / 64; ++it) {
      const int ml = it * 64 + lane;
      const float4 pm = pts[ml];
      const unsigned m = ch * CHUNK + ml;
      float dot = fmaf(qp.x, pm.x, fmaf(qp.y, pm.y, qp.z * pm.z));
      float d2 = qp.w + pm.w - 2.0f * dot;
      d2 = fmaxf(d2, 0.0f);
      unsigned long long key =
          ((unsigned long long)__float_as_uint(d2) << 32) | m;
      if (key < tau) {               // rarely wave-anytaken after chunk 0
        if (key < kk[KNN - 1]) {
          kk[KNN - 1] = key;
#pragma unroll
          for (int j = KNN - 1; j > 0; --j) {   // one bubble pass resorts
            unsigned long long a = kk[j - 1], bb = kk[j];
            kk[j - 1] = (bb < a) ? bb : a;
            kk[j]     = (bb < a) ? a : bb;
          }
        }
      }
    }
    tau = wave_min_u64(kk[KNN - 1]);   // refresh pruning threshold
  }

  // wave merge: 8 rounds of butterfly min; owner pops its head
  int ni_[KNN];
#pragma unroll
  for (int r = 0; r < KNN; ++r) {
    unsigned long long cmin = wave_min_u64(kk[0]);
    ni_[r] = (int)(unsigned)(cmin & 0xFFFFFFFFu);
    if (cmin == kk[0]) {   // unique owner (keys unique)
#pragma unroll
      for (int j = 0; j < KNN - 1; ++j) kk[j] = kk[j + 1];
      kk[KNN - 1] = ~0ull;
    }
  }

  // ---- attention over the 8 neighbors (output is order-invariant) ----
  const float lg = *log_gamma_p;
  const size_t qrow = (size_t)(base + n) * C_DIM;
  const float qv0 = q[qrow + lane];
  const float qv1 = q[qrow + lane + 64];

  float score[KNN];
#pragma unroll
  for (int j = 0; j < KNN; ++j) {
    const int mj = ni_[j];
    const size_t krow = (size_t)(base + mj) * C_DIM;
    float p = fmaf(qv1, k[krow + lane + 64], qv0 * k[krow + lane]);
#pragma unroll
    for (int off = 32; off > 0; off >>= 1) p += __shfl_xor(p, off, 64);
    // gamma from the diff-based safe norm (reference's second formula)
    const float4 pm = c4[base + mj];
    float dx = qp.x - pm.x, dy = qp.y - pm.y, dz = qp.z - pm.z;
    float d2p = fmaf(dx, dx, fmaf(dy, dy, dz * dz));
    float dist = d2p > 0.0f ? sqrtf(d2p) : 0.0f;
    float gw = expf(lg * dist);
    score[j] = (p / 11.313708498984761f) * gw;   // /sqrt(128) then *gamma
  }

  float mx = score[0];
#pragma unroll
  for (int j = 1; j < KNN; ++j) mx = fmaxf(mx, score[j]);
  float w[KNN]; float sum = 0.0f;
#pragma unroll
  for (int j = 0; j < KNN; ++j) { w[j] = expf(score[j] - mx); sum += w[j]; }
#pragma unroll
  for (int j = 0; j < KNN; ++j) w[j] = w[j] / sum;

  float a0 = 0.0f, a1 = 0.0f;
#pragma unroll
  for (int j = 0; j < KNN; ++j) {
    const size_t vrow = (size_t)(base + ni_[j]) * C_DIM;
    a0 = fmaf(w[j], v[vrow + lane], a0);
    a1 = fmaf(w[j], v[vrow + lane + 64], a1);
  }
  // agg aliases q's storage: safe, each q row is read only by its own wave
  agg[qrow + lane] = a0;
  agg[qrow + lane + 64] = a1;
}

// ---------------------------------------------------------------------------
extern "C" void kernel_launch(void* const* d_in, const int* in_sizes, int n_in,
                              void* d_out, int out_size, void* d_ws, size_t ws_size,
                              hipStream_t stream) {
  const float* feats  = (const float*)d_in[0];
  const float* coords = (const float*)d_in[1];
  const float* Wq     = (const float*)d_in[2];
  const float* Wk     = (const float*)d_in[3];
  const float* Wv     = (const float*)d_in[4];
  const float* Wo     = (const float*)d_in[5];
  const float* lg     = (const float*)d_in[6];
  float* out = (float*)d_out;

  float* ws = (float*)d_ws;
  const size_t ROWS = (size_t)M_TOTAL * C_DIM;   // 2,097,152 floats
  float*  q   = ws;                               // 8 MB
  float*  k   = ws + ROWS;                        // 8 MB
  float*  v   = ws + 2 * ROWS;                    // 8 MB
  float4* c4  = (float4*)(ws + 3 * ROWS);         // 256 KB, 16B-aligned
  float*  WTq = ws + 3 * ROWS + 4 * (size_t)M_TOTAL;
  float*  WTk = WTq + C_DIM * C_DIM;
  float*  WTv = WTk + C_DIM * C_DIM;
  float*  WTo = WTv + C_DIM * C_DIM;              // total ws use: ~24.8 MB
  float*  agg = q;                                // reuse q's buffer

  prep_coords<<<M_TOTAL / 256, 256, 0, stream>>>(coords, c4);
  transpose_w<<<256, 256, 0, stream>>>(Wq, Wk, Wv, Wo, WTq, WTk, WTv, WTo);
  gemm_qkv<<<M_TOTAL / 64, 256, 0, stream>>>(feats, WTq, WTk, WTv, q, k, v);
  knn_attn<<<M_TOTAL / 4, 256, 0, stream>>>(c4, q, k, v, lg, agg);
  gemm_xwt<<<M_TOTAL / 64, 256, 0, stream>>>(agg, WTo, out);
}

// Round 5
// 277.933 us; speedup vs baseline: 2.3745x; 1.3025x over previous
//
#include <hip/hip_runtime.h>
#include <math.h>

#define C_DIM 128
#define KNN 8
#define NPTS 8192
#define M_TOTAL 16384   // B*N
#define CHUNK 1024      // points staged in LDS per iteration of the KNN scan

// ---------------------------------------------------------------------------
// Kernel 1: coords -> packed float4 {x, y, z, |p|^2} per point
// ---------------------------------------------------------------------------
__global__ __launch_bounds__(256) void prep_coords(
    const float* __restrict__ coords, float4* __restrict__ c4) {
  int g = blockIdx.x * 256 + threadIdx.x;
  if (g < M_TOTAL) {
    float x = coords[3 * g + 0];
    float y = coords[3 * g + 1];
    float z = coords[3 * g + 2];
    // same fma ordering as the scan's dot product so self-distance cancels
    // to exactly 0.0f
    float s = fmaf(x, x, fmaf(y, y, z * z));
    c4[g] = make_float4(x, y, z, s);
  }
}

// ---------------------------------------------------------------------------
// Kernel 2: transpose the four 128x128 weight matrices once: WT[c][o]=W[o][c]
// ---------------------------------------------------------------------------
__global__ __launch_bounds__(256) void transpose_w(
    const float* __restrict__ Wq, const float* __restrict__ Wk,
    const float* __restrict__ Wv, const float* __restrict__ Wo,
    float* __restrict__ Tq, float* __restrict__ Tk,
    float* __restrict__ Tv, float* __restrict__ To) {
  int g = blockIdx.x * 256 + threadIdx.x;
  int mat = g >> 14;          // 0..3
  int j = g & 16383;          // dest linear index: j = c*128 + o
  int c = j >> 7, o = j & 127;
  const float* src = (mat == 0) ? Wq : (mat == 1) ? Wk : (mat == 2) ? Wv : Wo;
  float* dst = (mat == 0) ? Tq : (mat == 1) ? Tk : (mat == 2) ? Tv : To;
  dst[j] = src[o * C_DIM + c];   // coalesced write, strided (L2-hit) read
}

// ---------------------------------------------------------------------------
// GEMM body: 32-row X tile (staged in Xs) times one WT -> Y.
// 256 threads: 16 col-groups x 16 row-groups, 2 rows x 8 cols per thread.
// ---------------------------------------------------------------------------
__device__ __forceinline__ void gemm_tile32(
    const float (*Xs)[132], const float* __restrict__ WT,
    float* __restrict__ Y, int row0, int r0, int o0) {
  float acc[2][8];
#pragma unroll
  for (int i = 0; i < 2; ++i)
#pragma unroll
    for (int j = 0; j < 8; ++j) acc[i][j] = 0.0f;

  for (int c = 0; c < C_DIM; c += 4) {
    float xs[2][4];
#pragma unroll
    for (int i = 0; i < 2; ++i) {
      float4 xv = *(const float4*)&Xs[r0 + i][c];
      xs[i][0] = xv.x; xs[i][1] = xv.y; xs[i][2] = xv.z; xs[i][3] = xv.w;
    }
#pragma unroll
    for (int cc = 0; cc < 4; ++cc) {
      float4 wa = *(const float4*)&WT[(size_t)(c + cc) * C_DIM + o0];
      float4 wb = *(const float4*)&WT[(size_t)(c + cc) * C_DIM + o0 + 4];
#pragma unroll
      for (int i = 0; i < 2; ++i) {
        float x = xs[i][cc];
        acc[i][0] = fmaf(x, wa.x, acc[i][0]);
        acc[i][1] = fmaf(x, wa.y, acc[i][1]);
        acc[i][2] = fmaf(x, wa.z, acc[i][2]);
        acc[i][3] = fmaf(x, wa.w, acc[i][3]);
        acc[i][4] = fmaf(x, wb.x, acc[i][4]);
        acc[i][5] = fmaf(x, wb.y, acc[i][5]);
        acc[i][6] = fmaf(x, wb.z, acc[i][6]);
        acc[i][7] = fmaf(x, wb.w, acc[i][7]);
      }
    }
  }

#pragma unroll
  for (int i = 0; i < 2; ++i) {
    float* yrow = Y + (size_t)(row0 + r0 + i) * C_DIM + o0;
    *(float4*)yrow = make_float4(acc[i][0], acc[i][1], acc[i][2], acc[i][3]);
    *(float4*)(yrow + 4) = make_float4(acc[i][4], acc[i][5], acc[i][6], acc[i][7]);
  }
}

__device__ __forceinline__ void stage_x32(
    float (*Xs)[132], const float* __restrict__ X, int row0, int t) {
  const float4* X4 = (const float4*)(X + (size_t)row0 * C_DIM);
  for (int i = t; i < 32 * 32; i += 256) {
    int r = i >> 5, c4i = i & 31;
    *(float4*)&Xs[r][c4i * 4] = X4[i];
  }
}

// ---------------------------------------------------------------------------
// Kernel 3a: fused q/k/v projection — stage X tile once, apply 3 weights.
// 512 blocks -> 2 blocks/CU, 8 waves/CU (was 1 wave/SIMD: no latency hiding).
// ---------------------------------------------------------------------------
__global__ __launch_bounds__(256) void gemm_qkv(
    const float* __restrict__ X,
    const float* __restrict__ WTq, const float* __restrict__ WTk,
    const float* __restrict__ WTv,
    float* __restrict__ Yq, float* __restrict__ Yk, float* __restrict__ Yv) {
  __shared__ float Xs[32][132];
  const int t = threadIdx.x;
  const int row0 = blockIdx.x * 32;
  stage_x32(Xs, X, row0, t);
  __syncthreads();
  const int r0 = (t >> 4) * 2;
  const int o0 = (t & 15) * 8;
  gemm_tile32(Xs, WTq, Yq, row0, r0, o0);
  gemm_tile32(Xs, WTk, Yk, row0, r0, o0);
  gemm_tile32(Xs, WTv, Yv, row0, r0, o0);
}

// ---------------------------------------------------------------------------
// Kernel 3b: single GEMM (output projection)
// ---------------------------------------------------------------------------
__global__ __launch_bounds__(256) void gemm_xwt(
    const float* __restrict__ X, const float* __restrict__ WT,
    float* __restrict__ Y) {
  __shared__ float Xs[32][132];
  const int t = threadIdx.x;
  const int row0 = blockIdx.x * 32;
  stage_x32(Xs, X, row0, t);
  __syncthreads();
  const int r0 = (t >> 4) * 2;
  const int o0 = (t & 15) * 8;
  gemm_tile32(Xs, WT, Y, row0, r0, o0);
}

// ---------------------------------------------------------------------------
// Kernel 4: fused KNN + attention.
// Retention: per-lane sorted top-8 of u64 keys (bits(d2)<<32 | idx).
// Pruning: tau_f = EXACT wave 8th-smallest retained d2 (butterfly-min-with-
// pop over a u32 copy), refreshed after chunks 0,1,3. Guard d2<=tau_f is a
// provable superset of "can enter final top-8": >=8 retained floats <= tau_f
// always exist (7 popped rounds + round-8 min), so any skipped key has >=8
// smaller retained keys. Exactness preserved.
// ---------------------------------------------------------------------------
__device__ __forceinline__ unsigned long long wave_min_u64(unsigned long long x) {
#pragma unroll
  for (int off = 32; off > 0; off >>= 1) {
    unsigned long long o = __shfl_xor(x, off, 64);
    x = (o < x) ? o : x;
  }
  return x;
}

__device__ __forceinline__ float wave_8th_smallest(const unsigned long long kk[KNN]) {
  // u[] holds d2 bit patterns (non-negative floats: u32 order == float order);
  // per-lane arrays are sorted ascending already.
  unsigned u[KNN];
#pragma unroll
  for (int j = 0; j < KNN; ++j) u[j] = (unsigned)(kk[j] >> 32);
  unsigned m = 0;
#pragma unroll
  for (int r = 0; r < KNN; ++r) {
    m = u[0];
#pragma unroll
    for (int off = 32; off > 0; off >>= 1) {
      unsigned o = __shfl_xor(m, off, 64);
      m = (o < m) ? o : m;
    }
    bool mine = (u[0] == m);   // all lanes holding the min pop one element
#pragma unroll
    for (int j = 0; j < KNN - 1; ++j) u[j] = mine ? u[j + 1] : u[j];
    u[KNN - 1] = mine ? 0xFFFFFFFFu : u[KNN - 1];
  }
  return __uint_as_float(m);
}

__global__ __launch_bounds__(256) void knn_attn(
    const float4* __restrict__ c4,
    const float* __restrict__ q, const float* __restrict__ k,
    const float* __restrict__ v, const float* __restrict__ log_gamma_p,
    float* __restrict__ agg) {
  __shared__ float4 pts[CHUNK];   // 16 KB

  const int t = threadIdx.x;
  const int wave = t >> 6;
  const int lane = t & 63;
  const int qi = blockIdx.x * 4 + wave;          // blocks never straddle batch
  const int b = qi >> 13;
  const int n = qi & (NPTS - 1);
  const int base = b * NPTS;

  const float4 qp = c4[base + n];   // {x,y,z,|p|^2}

  // lane-local sorted top-8 of u64 keys, ascending; static indexing only
  unsigned long long kk[KNN];
#pragma unroll
  for (int j = 0; j < KNN; ++j) kk[j] = ~0ull;
  float tau_f = INFINITY;

  for (int ch = 0; ch < NPTS / CHUNK; ++ch) {
    __syncthreads();   // previous chunk fully consumed
    for (int i = t; i < CHUNK; i += 256) pts[i] = c4[base + ch * CHUNK + i];
    __syncthreads();

#pragma unroll 4
    for (int it = 0; it < CHUNK / 64; ++it) {
      const int ml = it * 64 + lane;
      const float4 pm = pts[ml];
      const unsigned m = ch * CHUNK + ml;
      float dot = fmaf(qp.x, pm.x, fmaf(qp.y, pm.y, qp.z * pm.z));
      float d2 = qp.w + pm.w - 2.0f * dot;
      d2 = fmaxf(d2, 0.0f);
      if (d2 <= tau_f) {             // exact-safe prune; rarely wave-anytaken
        unsigned long long key =
            ((unsigned long long)__float_as_uint(d2) << 32) | m;
        if (key < kk[KNN - 1]) {
          kk[KNN - 1] = key;
#pragma unroll
          for (int j = KNN - 1; j > 0; --j) {   // one bubble pass resorts
            unsigned long long a = kk[j - 1], bb = kk[j];
            kk[j - 1] = (bb < a) ? bb : a;
            kk[j]     = (bb < a) ? a : bb;
          }
        }
      }
    }
    if (ch == 0 || ch == 1 || ch == 3)
      tau_f = wave_8th_smallest(kk);   // exact global-8th refresh
  }

  // wave merge: 8 rounds of butterfly min; owner pops its head
  int ni_[KNN];
#pragma unroll
  for (int r = 0; r < KNN; ++r) {
    unsigned long long cmin = wave_min_u64(kk[0]);
    ni_[r] = (int)(unsigned)(cmin & 0xFFFFFFFFu);
    if (cmin == kk[0]) {   // unique owner (keys unique)
#pragma unroll
      for (int j = 0; j < KNN - 1; ++j) kk[j] = kk[j + 1];
      kk[KNN - 1] = ~0ull;
    }
  }

  // ---- attention over the 8 neighbors (output is order-invariant) ----
  const float lg = *log_gamma_p;
  const size_t qrow = (size_t)(base + n) * C_DIM;
  const float qv0 = q[qrow + lane];
  const float qv1 = q[qrow + lane + 64];

  float score[KNN];
#pragma unroll
  for (int j = 0; j < KNN; ++j) {
    const int mj = ni_[j];
    const size_t krow = (size_t)(base + mj) * C_DIM;
    float p = fmaf(qv1, k[krow + lane + 64], qv0 * k[krow + lane]);
#pragma unroll
    for (int off = 32; off > 0; off >>= 1) p += __shfl_xor(p, off, 64);
    // gamma from the diff-based safe norm (reference's second formula)
    const float4 pm = c4[base + mj];
    float dx = qp.x - pm.x, dy = qp.y - pm.y, dz = qp.z - pm.z;
    float d2p = fmaf(dx, dx, fmaf(dy, dy, dz * dz));
    float dist = d2p > 0.0f ? sqrtf(d2p) : 0.0f;
    float gw = expf(lg * dist);
    score[j] = (p / 11.313708498984761f) * gw;   // /sqrt(128) then *gamma
  }

  float mx = score[0];
#pragma unroll
  for (int j = 1; j < KNN; ++j) mx = fmaxf(mx, score[j]);
  float w[KNN]; float sum = 0.0f;
#pragma unroll
  for (int j = 0; j < KNN; ++j) { w[j] = expf(score[j] - mx); sum += w[j]; }
#pragma unroll
  for (int j = 0; j < KNN; ++j) w[j] = w[j] / sum;

  float a0 = 0.0f, a1 = 0.0f;
#pragma unroll
  for (int j = 0; j < KNN; ++j) {
    const size_t vrow = (size_t)(base + ni_[j]) * C_DIM;
    a0 = fmaf(w[j], v[vrow + lane], a0);
    a1 = fmaf(w[j], v[vrow + lane + 64], a1);
  }
  // agg aliases q's storage: safe, each q row is read only by its own wave
  agg[qrow + lane] = a0;
  agg[qrow + lane + 64] = a1;
}

// ---------------------------------------------------------------------------
extern "C" void kernel_launch(void* const* d_in, const int* in_sizes, int n_in,
                              void* d_out, int out_size, void* d_ws, size_t ws_size,
                              hipStream_t stream) {
  const float* feats  = (const float*)d_in[0];
  const float* coords = (const float*)d_in[1];
  const float* Wq     = (const float*)d_in[2];
  const float* Wk     = (const float*)d_in[3];
  const float* Wv     = (const float*)d_in[4];
  const float* Wo     = (const float*)d_in[5];
  const float* lg     = (const float*)d_in[6];
  float* out = (float*)d_out;

  float* ws = (float*)d_ws;
  const size_t ROWS = (size_t)M_TOTAL * C_DIM;   // 2,097,152 floats
  float*  q   = ws;                               // 8 MB
  float*  k   = ws + ROWS;                        // 8 MB
  float*  v   = ws + 2 * ROWS;                    // 8 MB
  float4* c4  = (float4*)(ws + 3 * ROWS);         // 256 KB, 16B-aligned
  float*  WTq = ws + 3 * ROWS + 4 * (size_t)M_TOTAL;
  float*  WTk = WTq + C_DIM * C_DIM;
  float*  WTv = WTk + C_DIM * C_DIM;
  float*  WTo = WTv + C_DIM * C_DIM;              // total ws use: ~24.8 MB
  float*  agg = q;                                // reuse q's buffer

  prep_coords<<<M_TOTAL / 256, 256, 0, stream>>>(coords, c4);
  transpose_w<<<256, 256, 0, stream>>>(Wq, Wk, Wv, Wo, WTq, WTk, WTv, WTo);
  gemm_qkv<<<M_TOTAL / 32, 256, 0, stream>>>(feats, WTq, WTk, WTv, q, k, v);
  knn_attn<<<M_TOTAL / 4, 256, 0, stream>>>(c4, q, k, v, lg, agg);
  gemm_xwt<<<M_TOTAL / 32, 256, 0, stream>>>(agg, WTo, out);
}

// Round 6
// 266.846 us; speedup vs baseline: 2.4731x; 1.0415x over previous
//
#include <hip/hip_runtime.h>
#include <math.h>

#define C_DIM 128
#define KNN 8
#define NPTS 8192
#define M_TOTAL 16384   // B*N
#define CHUNK 1024      // points staged in LDS per iteration of the KNN scan

typedef unsigned long long u64;

// ---------------------------------------------------------------------------
// Kernel 1: coords -> packed float4 {x, y, z, |p|^2} per point
// ---------------------------------------------------------------------------
__global__ __launch_bounds__(256) void prep_coords(
    const float* __restrict__ coords, float4* __restrict__ c4) {
  int g = blockIdx.x * 256 + threadIdx.x;
  if (g < M_TOTAL) {
    float x = coords[3 * g + 0];
    float y = coords[3 * g + 1];
    float z = coords[3 * g + 2];
    // same fma ordering as the scan's dot product so self-distance cancels
    // to exactly 0.0f
    float s = fmaf(x, x, fmaf(y, y, z * z));
    c4[g] = make_float4(x, y, z, s);
  }
}

// ---------------------------------------------------------------------------
// Kernel 2: transpose the four 128x128 weight matrices once: WT[c][o]=W[o][c]
// ---------------------------------------------------------------------------
__global__ __launch_bounds__(256) void transpose_w(
    const float* __restrict__ Wq, const float* __restrict__ Wk,
    const float* __restrict__ Wv, const float* __restrict__ Wo,
    float* __restrict__ Tq, float* __restrict__ Tk,
    float* __restrict__ Tv, float* __restrict__ To) {
  int g = blockIdx.x * 256 + threadIdx.x;
  int mat = g >> 14;          // 0..3
  int j = g & 16383;          // dest linear index: j = c*128 + o
  int c = j >> 7, o = j & 127;
  const float* src = (mat == 0) ? Wq : (mat == 1) ? Wk : (mat == 2) ? Wv : Wo;
  float* dst = (mat == 0) ? Tq : (mat == 1) ? Tk : (mat == 2) ? Tv : To;
  dst[j] = src[o * C_DIM + c];   // coalesced write, strided (L2-hit) read
}

// ---------------------------------------------------------------------------
__device__ __forceinline__ void stage_x64(
    float (*Xs)[132], const float* __restrict__ X, int row0, int t) {
  const float4* X4 = (const float4*)(X + (size_t)row0 * C_DIM);
  for (int i = t; i < 64 * 32; i += 256) {
    int r = i >> 5, c4i = i & 31;
    *(float4*)&Xs[r][c4i * 4] = X4[i];
  }
}

// ---------------------------------------------------------------------------
// Kernel 3a: fused q/k/v projection, interleaved in one c-loop.
// 64-row tiles (4 rows/thread W-reuse), one xs LDS read feeds 3 weights.
// 256 blocks x 256 threads; acc 3x[4][8].
// ---------------------------------------------------------------------------
__global__ __launch_bounds__(256) void gemm_qkv(
    const float* __restrict__ X,
    const float* __restrict__ WTq, const float* __restrict__ WTk,
    const float* __restrict__ WTv,
    float* __restrict__ Yq, float* __restrict__ Yk, float* __restrict__ Yv) {
  __shared__ float Xs[64][132];
  const int t = threadIdx.x;
  const int row0 = blockIdx.x * 64;
  stage_x64(Xs, X, row0, t);
  __syncthreads();

  const int r0 = (t >> 4) * 4;
  const int o0 = (t & 15) * 8;

  float aq[4][8], ak[4][8], av[4][8];
#pragma unroll
  for (int i = 0; i < 4; ++i)
#pragma unroll
    for (int j = 0; j < 8; ++j) { aq[i][j] = 0.f; ak[i][j] = 0.f; av[i][j] = 0.f; }

  for (int c = 0; c < C_DIM; c += 4) {
    float xs[4][4];
#pragma unroll
    for (int i = 0; i < 4; ++i) {
      float4 xv = *(const float4*)&Xs[r0 + i][c];
      xs[i][0] = xv.x; xs[i][1] = xv.y; xs[i][2] = xv.z; xs[i][3] = xv.w;
    }
#pragma unroll
    for (int cc = 0; cc < 4; ++cc) {
      const size_t wrow = (size_t)(c + cc) * C_DIM + o0;
      float4 qa = *(const float4*)&WTq[wrow];
      float4 qb = *(const float4*)&WTq[wrow + 4];
      float4 ka = *(const float4*)&WTk[wrow];
      float4 kb = *(const float4*)&WTk[wrow + 4];
      float4 va = *(const float4*)&WTv[wrow];
      float4 vb = *(const float4*)&WTv[wrow + 4];
#pragma unroll
      for (int i = 0; i < 4; ++i) {
        float x = xs[i][cc];
        aq[i][0] = fmaf(x, qa.x, aq[i][0]); aq[i][1] = fmaf(x, qa.y, aq[i][1]);
        aq[i][2] = fmaf(x, qa.z, aq[i][2]); aq[i][3] = fmaf(x, qa.w, aq[i][3]);
        aq[i][4] = fmaf(x, qb.x, aq[i][4]); aq[i][5] = fmaf(x, qb.y, aq[i][5]);
        aq[i][6] = fmaf(x, qb.z, aq[i][6]); aq[i][7] = fmaf(x, qb.w, aq[i][7]);
        ak[i][0] = fmaf(x, ka.x, ak[i][0]); ak[i][1] = fmaf(x, ka.y, ak[i][1]);
        ak[i][2] = fmaf(x, ka.z, ak[i][2]); ak[i][3] = fmaf(x, ka.w, ak[i][3]);
        ak[i][4] = fmaf(x, kb.x, ak[i][4]); ak[i][5] = fmaf(x, kb.y, ak[i][5]);
        ak[i][6] = fmaf(x, kb.z, ak[i][6]); ak[i][7] = fmaf(x, kb.w, ak[i][7]);
        av[i][0] = fmaf(x, va.x, av[i][0]); av[i][1] = fmaf(x, va.y, av[i][1]);
        av[i][2] = fmaf(x, va.z, av[i][2]); av[i][3] = fmaf(x, va.w, av[i][3]);
        av[i][4] = fmaf(x, vb.x, av[i][4]); av[i][5] = fmaf(x, vb.y, av[i][5]);
        av[i][6] = fmaf(x, vb.z, av[i][6]); av[i][7] = fmaf(x, vb.w, av[i][7]);
      }
    }
  }

#pragma unroll
  for (int i = 0; i < 4; ++i) {
    const size_t yoff = (size_t)(row0 + r0 + i) * C_DIM + o0;
    *(float4*)&Yq[yoff] = make_float4(aq[i][0], aq[i][1], aq[i][2], aq[i][3]);
    *(float4*)&Yq[yoff + 4] = make_float4(aq[i][4], aq[i][5], aq[i][6], aq[i][7]);
    *(float4*)&Yk[yoff] = make_float4(ak[i][0], ak[i][1], ak[i][2], ak[i][3]);
    *(float4*)&Yk[yoff + 4] = make_float4(ak[i][4], ak[i][5], ak[i][6], ak[i][7]);
    *(float4*)&Yv[yoff] = make_float4(av[i][0], av[i][1], av[i][2], av[i][3]);
    *(float4*)&Yv[yoff + 4] = make_float4(av[i][4], av[i][5], av[i][6], av[i][7]);
  }
}

// ---------------------------------------------------------------------------
// Kernel 3b: single GEMM (output projection), 64-row tiles.
// ---------------------------------------------------------------------------
__global__ __launch_bounds__(256) void gemm_xwt(
    const float* __restrict__ X, const float* __restrict__ WT,
    float* __restrict__ Y) {
  __shared__ float Xs[64][132];
  const int t = threadIdx.x;
  const int row0 = blockIdx.x * 64;
  stage_x64(Xs, X, row0, t);
  __syncthreads();

  const int r0 = (t >> 4) * 4;
  const int o0 = (t & 15) * 8;

  float acc[4][8];
#pragma unroll
  for (int i = 0; i < 4; ++i)
#pragma unroll
    for (int j = 0; j < 8; ++j) acc[i][j] = 0.0f;

  for (int c = 0; c < C_DIM; c += 4) {
    float xs[4][4];
#pragma unroll
    for (int i = 0; i < 4; ++i) {
      float4 xv = *(const float4*)&Xs[r0 + i][c];
      xs[i][0] = xv.x; xs[i][1] = xv.y; xs[i][2] = xv.z; xs[i][3] = xv.w;
    }
#pragma unroll
    for (int cc = 0; cc < 4; ++cc) {
      const size_t wrow = (size_t)(c + cc) * C_DIM + o0;
      float4 wa = *(const float4*)&WT[wrow];
      float4 wb = *(const float4*)&WT[wrow + 4];
#pragma unroll
      for (int i = 0; i < 4; ++i) {
        float x = xs[i][cc];
        acc[i][0] = fmaf(x, wa.x, acc[i][0]); acc[i][1] = fmaf(x, wa.y, acc[i][1]);
        acc[i][2] = fmaf(x, wa.z, acc[i][2]); acc[i][3] = fmaf(x, wa.w, acc[i][3]);
        acc[i][4] = fmaf(x, wb.x, acc[i][4]); acc[i][5] = fmaf(x, wb.y, acc[i][5]);
        acc[i][6] = fmaf(x, wb.z, acc[i][6]); acc[i][7] = fmaf(x, wb.w, acc[i][7]);
      }
    }
  }

#pragma unroll
  for (int i = 0; i < 4; ++i) {
    float* yrow = Y + (size_t)(row0 + r0 + i) * C_DIM + o0;
    *(float4*)yrow = make_float4(acc[i][0], acc[i][1], acc[i][2], acc[i][3]);
    *(float4*)(yrow + 4) = make_float4(acc[i][4], acc[i][5], acc[i][6], acc[i][7]);
  }
}

// ---------------------------------------------------------------------------
// Kernel 4: fused KNN + attention.
// Retention: per-lane sorted top-8 of u64 keys (bits(d2)<<32 | idx).
// Pruning: tau_f = EXACT wave 8th-smallest retained d2, refreshed after
// chunks 0,1,3 (safe: >=8 retained keys <= tau_f always exist).
// NEW: insert region guarded by __any() -> wave-uniform s_cbranch, so the
// ~50-instr predicated insert body is only ISSUED on anytaken iterations
// (compiler was if-converting the plain divergent guard -> issued always).
// 2 points per lane per iteration halves loop/branch overhead.
// ---------------------------------------------------------------------------
__device__ __forceinline__ u64 wave_min_u64(u64 x) {
#pragma unroll
  for (int off = 32; off > 0; off >>= 1) {
    u64 o = __shfl_xor(x, off, 64);
    x = (o < x) ? o : x;
  }
  return x;
}

__device__ __forceinline__ float wave_8th_smallest(const u64 kk[KNN]) {
  unsigned u[KNN];
#pragma unroll
  for (int j = 0; j < KNN; ++j) u[j] = (unsigned)(kk[j] >> 32);
  unsigned m = 0;
#pragma unroll
  for (int r = 0; r < KNN; ++r) {
    m = u[0];
#pragma unroll
    for (int off = 32; off > 0; off >>= 1) {
      unsigned o = __shfl_xor(m, off, 64);
      m = (o < m) ? o : m;
    }
    bool mine = (u[0] == m);   // all lanes holding the min pop one element
#pragma unroll
    for (int j = 0; j < KNN - 1; ++j) u[j] = mine ? u[j + 1] : u[j];
    u[KNN - 1] = mine ? 0xFFFFFFFFu : u[KNN - 1];
  }
  return __uint_as_float(m);
}

__device__ __forceinline__ void insert_key(u64 (&kk)[KNN], u64 key) {
  if (key < kk[KNN - 1]) {
    kk[KNN - 1] = key;
#pragma unroll
    for (int j = KNN - 1; j > 0; --j) {   // one bubble pass resorts
      u64 a = kk[j - 1], bb = kk[j];
      kk[j - 1] = (bb < a) ? bb : a;
      kk[j]     = (bb < a) ? a : bb;
    }
  }
}

__global__ __launch_bounds__(256) void knn_attn(
    const float4* __restrict__ c4,
    const float* __restrict__ q, const float* __restrict__ k,
    const float* __restrict__ v, const float* __restrict__ log_gamma_p,
    float* __restrict__ agg) {
  __shared__ float4 pts[CHUNK];   // 16 KB

  const int t = threadIdx.x;
  const int wave = t >> 6;
  const int lane = t & 63;
  const int qi = blockIdx.x * 4 + wave;          // blocks never straddle batch
  const int b = qi >> 13;
  const int n = qi & (NPTS - 1);
  const int base = b * NPTS;

  const float4 qp = c4[base + n];   // {x,y,z,|p|^2}

  u64 kk[KNN];
#pragma unroll
  for (int j = 0; j < KNN; ++j) kk[j] = ~0ull;
  float tau_f = INFINITY;

  for (int ch = 0; ch < NPTS / CHUNK; ++ch) {
    __syncthreads();   // previous chunk fully consumed
    for (int i = t; i < CHUNK; i += 256) pts[i] = c4[base + ch * CHUNK + i];
    __syncthreads();

#pragma unroll
    for (int it = 0; it < CHUNK / 128; ++it) {   // 2 points per lane per iter
      const int ml = it * 128 + lane;
      const float4 pa = pts[ml];
      const float4 pb = pts[ml + 64];
      float dota = fmaf(qp.x, pa.x, fmaf(qp.y, pa.y, qp.z * pa.z));
      float dotb = fmaf(qp.x, pb.x, fmaf(qp.y, pb.y, qp.z * pb.z));
      float d2a = qp.w + pa.w - 2.0f * dota;   // unclamped; decision-identical
      float d2b = qp.w + pb.w - 2.0f * dotb;   // since tau_f >= 0
      bool ga = d2a <= tau_f;
      bool gb = d2b <= tau_f;
      if (__builtin_expect(__any(ga | gb), 0)) {   // wave-uniform branch
        if (ga) {
          float ca = fmaxf(d2a, 0.0f);
          insert_key(kk, ((u64)__float_as_uint(ca) << 32) |
                             (unsigned)(ch * CHUNK + ml));
        }
        if (gb) {
          float cb = fmaxf(d2b, 0.0f);
          insert_key(kk, ((u64)__float_as_uint(cb) << 32) |
                             (unsigned)(ch * CHUNK + ml + 64));
        }
      }
    }
    if (ch == 0 || ch == 1 || ch == 3)
      tau_f = wave_8th_smallest(kk);   // exact global-8th refresh
  }

  // wave merge: 8 rounds of butterfly min; owner pops its head
  int ni_[KNN];
#pragma unroll
  for (int r = 0; r < KNN; ++r) {
    u64 cmin = wave_min_u64(kk[0]);
    ni_[r] = (int)(unsigned)(cmin & 0xFFFFFFFFu);
    if (cmin == kk[0]) {   // unique owner (keys unique)
#pragma unroll
      for (int j = 0; j < KNN - 1; ++j) kk[j] = kk[j + 1];
      kk[KNN - 1] = ~0ull;
    }
  }

  // ---- attention over the 8 neighbors (output is order-invariant) ----
  const float lg = *log_gamma_p;
  const size_t qrow = (size_t)(base + n) * C_DIM;
  const float qv0 = q[qrow + lane];
  const float qv1 = q[qrow + lane + 64];

  float score[KNN];
#pragma unroll
  for (int j = 0; j < KNN; ++j) {
    const int mj = ni_[j];
    const size_t krow = (size_t)(base + mj) * C_DIM;
    float p = fmaf(qv1, k[krow + lane + 64], qv0 * k[krow + lane]);
#pragma unroll
    for (int off = 32; off > 0; off >>= 1) p += __shfl_xor(p, off, 64);
    // gamma from the diff-based safe norm (reference's second formula)
    const float4 pm = c4[base + mj];
    float dx = qp.x - pm.x, dy = qp.y - pm.y, dz = qp.z - pm.z;
    float d2p = fmaf(dx, dx, fmaf(dy, dy, dz * dz));
    float dist = d2p > 0.0f ? sqrtf(d2p) : 0.0f;
    float gw = expf(lg * dist);
    score[j] = (p / 11.313708498984761f) * gw;   // /sqrt(128) then *gamma
  }

  float mx = score[0];
#pragma unroll
  for (int j = 1; j < KNN; ++j) mx = fmaxf(mx, score[j]);
  float w[KNN]; float sum = 0.0f;
#pragma unroll
  for (int j = 0; j < KNN; ++j) { w[j] = expf(score[j] - mx); sum += w[j]; }
#pragma unroll
  for (int j = 0; j < KNN; ++j) w[j] = w[j] / sum;

  float a0 = 0.0f, a1 = 0.0f;
#pragma unroll
  for (int j = 0; j < KNN; ++j) {
    const size_t vrow = (size_t)(base + ni_[j]) * C_DIM;
    a0 = fmaf(w[j], v[vrow + lane], a0);
    a1 = fmaf(w[j], v[vrow + lane + 64], a1);
  }
  // agg aliases q's storage: safe, each q row is read only by its own wave
  agg[qrow + lane] = a0;
  agg[qrow + lane + 64] = a1;
}

// ---------------------------------------------------------------------------
extern "C" void kernel_launch(void* const* d_in, const int* in_sizes, int n_in,
                              void* d_out, int out_size, void* d_ws, size_t ws_size,
                              hipStream_t stream) {
  const float* feats  = (const float*)d_in[0];
  const float* coords = (const float*)d_in[1];
  const float* Wq     = (const float*)d_in[2];
  const float* Wk     = (const float*)d_in[3];
  const float* Wv     = (const float*)d_in[4];
  const float* Wo     = (const float*)d_in[5];
  const float* lg     = (const float*)d_in[6];
  float* out = (float*)d_out;

  float* ws = (float*)d_ws;
  const size_t ROWS = (size_t)M_TOTAL * C_DIM;   // 2,097,152 floats
  float*  q   = ws;                               // 8 MB
  float*  k   = ws + ROWS;                        // 8 MB
  float*  v   = ws + 2 * ROWS;                    // 8 MB
  float4* c4  = (float4*)(ws + 3 * ROWS);         // 256 KB, 16B-aligned
  float*  WTq = ws + 3 * ROWS + 4 * (size_t)M_TOTAL;
  float*  WTk = WTq + C_DIM * C_DIM;
  float*  WTv = WTk + C_DIM * C_DIM;
  float*  WTo = WTv + C_DIM * C_DIM;              // total ws use: ~24.8 MB
  float*  agg = q;                                // reuse q's buffer

  prep_coords<<<M_TOTAL / 256, 256, 0, stream>>>(coords, c4);
  transpose_w<<<256, 256, 0, stream>>>(Wq, Wk, Wv, Wo, WTq, WTk, WTv, WTo);
  gemm_qkv<<<M_TOTAL / 64, 256, 0, stream>>>(feats, WTq, WTk, WTv, q, k, v);
  knn_attn<<<M_TOTAL / 4, 256, 0, stream>>>(c4, q, k, v, lg, agg);
  gemm_xwt<<<M_TOTAL / 64, 256, 0, stream>>>(agg, WTo, out);
}

// Round 7
// 256.946 us; speedup vs baseline: 2.5684x; 1.0385x over previous
//
#include <hip/hip_runtime.h>
#include <math.h>

#define C_DIM 128
#define KNN 8
#define NPTS 8192
#define M_TOTAL 16384   // B*N
#define CHUNK 1024      // points staged in LDS per iteration of the KNN scan
#define CAND_CAP 64     // per-wave candidate buffer (expected use: 8-16)

typedef unsigned long long u64;

// ---------------------------------------------------------------------------
// Kernel 1: coords -> packed float4 {x, y, z, |p|^2} per point
// ---------------------------------------------------------------------------
__global__ __launch_bounds__(256) void prep_coords(
    const float* __restrict__ coords, float4* __restrict__ c4) {
  int g = blockIdx.x * 256 + threadIdx.x;
  if (g < M_TOTAL) {
    float x = coords[3 * g + 0];
    float y = coords[3 * g + 1];
    float z = coords[3 * g + 2];
    // same fma ordering as the scan's dot product so self-distance cancels
    // to exactly 0.0f
    float s = fmaf(x, x, fmaf(y, y, z * z));
    c4[g] = make_float4(x, y, z, s);
  }
}

// ---------------------------------------------------------------------------
// Kernel 2: transpose the four 128x128 weight matrices once: WT[c][o]=W[o][c]
// ---------------------------------------------------------------------------
__global__ __launch_bounds__(256) void transpose_w(
    const float* __restrict__ Wq, const float* __restrict__ Wk,
    const float* __restrict__ Wv, const float* __restrict__ Wo,
    float* __restrict__ Tq, float* __restrict__ Tk,
    float* __restrict__ Tv, float* __restrict__ To) {
  int g = blockIdx.x * 256 + threadIdx.x;
  int mat = g >> 14;          // 0..3
  int j = g & 16383;          // dest linear index: j = c*128 + o
  int c = j >> 7, o = j & 127;
  const float* src = (mat == 0) ? Wq : (mat == 1) ? Wk : (mat == 2) ? Wv : Wo;
  float* dst = (mat == 0) ? Tq : (mat == 1) ? Tk : (mat == 2) ? Tv : To;
  dst[j] = src[o * C_DIM + c];   // coalesced write, strided (L2-hit) read
}

// ---------------------------------------------------------------------------
__device__ __forceinline__ void stage_x64(
    float (*Xs)[132], const float* __restrict__ X, int row0, int t) {
  const float4* X4 = (const float4*)(X + (size_t)row0 * C_DIM);
  for (int i = t; i < 64 * 32; i += 256) {
    int r = i >> 5, c4i = i & 31;
    *(float4*)&Xs[r][c4i * 4] = X4[i];
  }
}

// ---------------------------------------------------------------------------
// Kernel 3a: fused q/k/v projection, interleaved in one c-loop.
// 64-row tiles (4 rows/thread W-reuse), one xs LDS read feeds 3 weights.
// ---------------------------------------------------------------------------
__global__ __launch_bounds__(256) void gemm_qkv(
    const float* __restrict__ X,
    const float* __restrict__ WTq, const float* __restrict__ WTk,
    const float* __restrict__ WTv,
    float* __restrict__ Yq, float* __restrict__ Yk, float* __restrict__ Yv) {
  __shared__ float Xs[64][132];
  const int t = threadIdx.x;
  const int row0 = blockIdx.x * 64;
  stage_x64(Xs, X, row0, t);
  __syncthreads();

  const int r0 = (t >> 4) * 4;
  const int o0 = (t & 15) * 8;

  float aq[4][8], ak[4][8], av[4][8];
#pragma unroll
  for (int i = 0; i < 4; ++i)
#pragma unroll
    for (int j = 0; j < 8; ++j) { aq[i][j] = 0.f; ak[i][j] = 0.f; av[i][j] = 0.f; }

  for (int c = 0; c < C_DIM; c += 4) {
    float xs[4][4];
#pragma unroll
    for (int i = 0; i < 4; ++i) {
      float4 xv = *(const float4*)&Xs[r0 + i][c];
      xs[i][0] = xv.x; xs[i][1] = xv.y; xs[i][2] = xv.z; xs[i][3] = xv.w;
    }
#pragma unroll
    for (int cc = 0; cc < 4; ++cc) {
      const size_t wrow = (size_t)(c + cc) * C_DIM + o0;
      float4 qa = *(const float4*)&WTq[wrow];
      float4 qb = *(const float4*)&WTq[wrow + 4];
      float4 ka = *(const float4*)&WTk[wrow];
      float4 kb = *(const float4*)&WTk[wrow + 4];
      float4 va = *(const float4*)&WTv[wrow];
      float4 vb = *(const float4*)&WTv[wrow + 4];
#pragma unroll
      for (int i = 0; i < 4; ++i) {
        float x = xs[i][cc];
        aq[i][0] = fmaf(x, qa.x, aq[i][0]); aq[i][1] = fmaf(x, qa.y, aq[i][1]);
        aq[i][2] = fmaf(x, qa.z, aq[i][2]); aq[i][3] = fmaf(x, qa.w, aq[i][3]);
        aq[i][4] = fmaf(x, qb.x, aq[i][4]); aq[i][5] = fmaf(x, qb.y, aq[i][5]);
        aq[i][6] = fmaf(x, qb.z, aq[i][6]); aq[i][7] = fmaf(x, qb.w, aq[i][7]);
        ak[i][0] = fmaf(x, ka.x, ak[i][0]); ak[i][1] = fmaf(x, ka.y, ak[i][1]);
        ak[i][2] = fmaf(x, ka.z, ak[i][2]); ak[i][3] = fmaf(x, ka.w, ak[i][3]);
        ak[i][4] = fmaf(x, kb.x, ak[i][4]); ak[i][5] = fmaf(x, kb.y, ak[i][5]);
        ak[i][6] = fmaf(x, kb.z, ak[i][6]); ak[i][7] = fmaf(x, kb.w, ak[i][7]);
        av[i][0] = fmaf(x, va.x, av[i][0]); av[i][1] = fmaf(x, va.y, av[i][1]);
        av[i][2] = fmaf(x, va.z, av[i][2]); av[i][3] = fmaf(x, va.w, av[i][3]);
        av[i][4] = fmaf(x, vb.x, av[i][4]); av[i][5] = fmaf(x, vb.y, av[i][5]);
        av[i][6] = fmaf(x, vb.z, av[i][6]); av[i][7] = fmaf(x, vb.w, av[i][7]);
      }
    }
  }

#pragma unroll
  for (int i = 0; i < 4; ++i) {
    const size_t yoff = (size_t)(row0 + r0 + i) * C_DIM + o0;
    *(float4*)&Yq[yoff] = make_float4(aq[i][0], aq[i][1], aq[i][2], aq[i][3]);
    *(float4*)&Yq[yoff + 4] = make_float4(aq[i][4], aq[i][5], aq[i][6], aq[i][7]);
    *(float4*)&Yk[yoff] = make_float4(ak[i][0], ak[i][1], ak[i][2], ak[i][3]);
    *(float4*)&Yk[yoff + 4] = make_float4(ak[i][4], ak[i][5], ak[i][6], ak[i][7]);
    *(float4*)&Yv[yoff] = make_float4(av[i][0], av[i][1], av[i][2], av[i][3]);
    *(float4*)&Yv[yoff + 4] = make_float4(av[i][4], av[i][5], av[i][6], av[i][7]);
  }
}

// ---------------------------------------------------------------------------
// Kernel 3b: single GEMM (output projection), 64-row tiles.
// ---------------------------------------------------------------------------
__global__ __launch_bounds__(256) void gemm_xwt(
    const float* __restrict__ X, const float* __restrict__ WT,
    float* __restrict__ Y) {
  __shared__ float Xs[64][132];
  const int t = threadIdx.x;
  const int row0 = blockIdx.x * 64;
  stage_x64(Xs, X, row0, t);
  __syncthreads();

  const int r0 = (t >> 4) * 4;
  const int o0 = (t & 15) * 8;

  float acc[4][8];
#pragma unroll
  for (int i = 0; i < 4; ++i)
#pragma unroll
    for (int j = 0; j < 8; ++j) acc[i][j] = 0.0f;

  for (int c = 0; c < C_DIM; c += 4) {
    float xs[4][4];
#pragma unroll
    for (int i = 0; i < 4; ++i) {
      float4 xv = *(const float4*)&Xs[r0 + i][c];
      xs[i][0] = xv.x; xs[i][1] = xv.y; xs[i][2] = xv.z; xs[i][3] = xv.w;
    }
#pragma unroll
    for (int cc = 0; cc < 4; ++cc) {
      const size_t wrow = (size_t)(c + cc) * C_DIM + o0;
      float4 wa = *(const float4*)&WT[wrow];
      float4 wb = *(const float4*)&WT[wrow + 4];
#pragma unroll
      for (int i = 0; i < 4; ++i) {
        float x = xs[i][cc];
        acc[i][0] = fmaf(x, wa.x, acc[i][0]); acc[i][1] = fmaf(x, wa.y, acc[i][1]);
        acc[i][2] = fmaf(x, wa.z, acc[i][2]); acc[i][3] = fmaf(x, wa.w, acc[i][3]);
        acc[i][4] = fmaf(x, wb.x, acc[i][4]); acc[i][5] = fmaf(x, wb.y, acc[i][5]);
        acc[i][6] = fmaf(x, wb.z, acc[i][6]); acc[i][7] = fmaf(x, wb.w, acc[i][7]);
      }
    }
  }

#pragma unroll
  for (int i = 0; i < 4; ++i) {
    float* yrow = Y + (size_t)(row0 + r0 + i) * C_DIM + o0;
    *(float4*)yrow = make_float4(acc[i][0], acc[i][1], acc[i][2], acc[i][3]);
    *(float4*)(yrow + 4) = make_float4(acc[i][4], acc[i][5], acc[i][6], acc[i][7]);
  }
}

// ---------------------------------------------------------------------------
// Kernel 4: fused KNN + attention. TWO-PASS exact top-8:
//  Pass A: per-lane top-8 of clamped d2 VALUES only — branchless
//          v_min/v_max bubble (16 ops/pt, no branches, no u64, no cndmask).
//  tau8:   wave-global 8th-smallest retained value via butterfly-min-pop.
//          Cross-lane duplicate values pop >=1/round -> tau8 >= true s8
//          (safe superset bound, tau8 <= s16 -> <=16+ties candidates).
//  Pass B: re-scan; d2 <= tau8 -> ballot-compact (d2,idx) u64 keys into a
//          per-wave LDS buffer (rarely-taken body); final 8 = butterfly-min-
//          pop over candidates = exact lex-(d2, idx) top_k semantics.
// ---------------------------------------------------------------------------
__device__ __forceinline__ u64 wave_min_u64(u64 x) {
#pragma unroll
  for (int off = 32; off > 0; off >>= 1) {
    u64 o = __shfl_xor(x, off, 64);
    x = (o < x) ? o : x;
  }
  return x;
}

// branchless insert of e into ascending 8-array of smallest values
__device__ __forceinline__ void bubble8(float (&kk)[KNN], float e) {
#pragma unroll
  for (int j = 0; j < KNN; ++j) {
    float lo = fminf(kk[j], e);
    float hi = fmaxf(kk[j], e);
    kk[j] = lo;
    e = hi;   // e exits as the dropped (9th) value
  }
}

// wave-global ~8th smallest (>= s8, <= s16 under cross-lane value dups)
__device__ __forceinline__ float wave_8th_smallest_f32(const float kk[KNN]) {
  float u[KNN];
#pragma unroll
  for (int j = 0; j < KNN; ++j) u[j] = kk[j];
  float m = 0.0f;
#pragma unroll
  for (int r = 0; r < KNN; ++r) {
    m = u[0];   // per-lane arrays ascending -> u[0] is lane min
#pragma unroll
    for (int off = 32; off > 0; off >>= 1) {
      float o = __shfl_xor(m, off, 64);
      m = fminf(m, o);
    }
    bool mine = (u[0] == m);   // every lane holding m pops one element
#pragma unroll
    for (int j = 0; j < KNN - 1; ++j) u[j] = mine ? u[j + 1] : u[j];
    u[KNN - 1] = mine ? INFINITY : u[KNN - 1];
  }
  return m;
}

__global__ __launch_bounds__(256) void knn_attn(
    const float4* __restrict__ c4,
    const float* __restrict__ q, const float* __restrict__ k,
    const float* __restrict__ v, const float* __restrict__ log_gamma_p,
    float* __restrict__ agg) {
  __shared__ float4 pts[CHUNK];          // 16 KB
  __shared__ u64 cand[4][CAND_CAP];      // 2 KB, per-wave candidate buffers

  const int t = threadIdx.x;
  const int wave = t >> 6;
  const int lane = t & 63;
  const int qi = blockIdx.x * 4 + wave;          // blocks never straddle batch
  const int b = qi >> 13;
  const int n = qi & (NPTS - 1);
  const int base = b * NPTS;

  const float4 qp = c4[base + n];   // {x,y,z,|p|^2}
  const u64 lmask = (1ull << lane) - 1ull;

  // ---------------- pass A: values-only top-8, branchless ----------------
  float kk[KNN];
#pragma unroll
  for (int j = 0; j < KNN; ++j) kk[j] = INFINITY;

  for (int ch = 0; ch < NPTS / CHUNK; ++ch) {
    __syncthreads();   // previous chunk fully consumed
    for (int i = t; i < CHUNK; i += 256) pts[i] = c4[base + ch * CHUNK + i];
    __syncthreads();

#pragma unroll
    for (int it = 0; it < CHUNK / 128; ++it) {   // 2 points per lane per iter
      const int ml = it * 128 + lane;
      const float4 pa = pts[ml];
      const float4 pb = pts[ml + 64];
      float dota = fmaf(qp.x, pa.x, fmaf(qp.y, pa.y, qp.z * pa.z));
      float dotb = fmaf(qp.x, pb.x, fmaf(qp.y, pb.y, qp.z * pb.z));
      float d2a = fmaxf(qp.w + pa.w - 2.0f * dota, 0.0f);
      float d2b = fmaxf(qp.w + pb.w - 2.0f * dotb, 0.0f);
      bubble8(kk, d2a);
      bubble8(kk, d2b);
    }
  }

  const float tau8 = wave_8th_smallest_f32(kk);

  // ---------------- pass B: collect candidates with d2 <= tau8 -----------
  int cnt = 0;
  for (int ch = 0; ch < NPTS / CHUNK; ++ch) {
    __syncthreads();
    for (int i = t; i < CHUNK; i += 256) pts[i] = c4[base + ch * CHUNK + i];
    __syncthreads();

#pragma unroll
    for (int it = 0; it < CHUNK / 128; ++it) {
      const int ml = it * 128 + lane;
      const float4 pa = pts[ml];
      const float4 pb = pts[ml + 64];
      float dota = fmaf(qp.x, pa.x, fmaf(qp.y, pa.y, qp.z * pa.z));
      float dotb = fmaf(qp.x, pb.x, fmaf(qp.y, pb.y, qp.z * pb.z));
      float d2a = fmaxf(qp.w + pa.w - 2.0f * dota, 0.0f);
      float d2b = fmaxf(qp.w + pb.w - 2.0f * dotb, 0.0f);
      bool ga = d2a <= tau8;
      bool gb = d2b <= tau8;
      u64 mska = __ballot(ga);
      u64 mskb = __ballot(gb);
      if (mska | mskb) {   // rarely-taken, wave-uniform scalar branch
        if (ga) {
          int pos = cnt + (int)__popcll(mska & lmask);
          if (pos < CAND_CAP)
            cand[wave][pos] = ((u64)__float_as_uint(d2a) << 32) |
                              (unsigned)(ch * CHUNK + ml);
        }
        cnt += (int)__popcll(mska);
        if (gb) {
          int pos = cnt + (int)__popcll(mskb & lmask);
          if (pos < CAND_CAP)
            cand[wave][pos] = ((u64)__float_as_uint(d2b) << 32) |
                              (unsigned)(ch * CHUNK + ml + 64);
        }
        cnt += (int)__popcll(mskb);
      }
    }
  }

  // ------------- final exact top-8 over candidates (lex (d2, idx)) -------
  const int m_ = (cnt < CAND_CAP) ? cnt : CAND_CAP;
  u64 mykey = (lane < m_) ? cand[wave][lane] : ~0ull;
  int ni_[KNN];
#pragma unroll
  for (int r = 0; r < KNN; ++r) {
    u64 mm = wave_min_u64(mykey);
    ni_[r] = (int)(unsigned)(mm & 0xFFFFFFFFu);
    if (mykey == mm) mykey = ~0ull;   // keys unique: single owner pops
  }

  // ---- attention over the 8 neighbors (output is order-invariant) ----
  const float lg = *log_gamma_p;
  const size_t qrow = (size_t)(base + n) * C_DIM;
  const float qv0 = q[qrow + lane];
  const float qv1 = q[qrow + lane + 64];

  float score[KNN];
#pragma unroll
  for (int j = 0; j < KNN; ++j) {
    const int mj = ni_[j];
    const size_t krow = (size_t)(base + mj) * C_DIM;
    float p = fmaf(qv1, k[krow + lane + 64], qv0 * k[krow + lane]);
#pragma unroll
    for (int off = 32; off > 0; off >>= 1) p += __shfl_xor(p, off, 64);
    // gamma from the diff-based safe norm (reference's second formula)
    const float4 pm = c4[base + mj];
    float dx = qp.x - pm.x, dy = qp.y - pm.y, dz = qp.z - pm.z;
    float d2p = fmaf(dx, dx, fmaf(dy, dy, dz * dz));
    float dist = d2p > 0.0f ? sqrtf(d2p) : 0.0f;
    float gw = expf(lg * dist);
    score[j] = (p / 11.313708498984761f) * gw;   // /sqrt(128) then *gamma
  }

  float mx = score[0];
#pragma unroll
  for (int j = 1; j < KNN; ++j) mx = fmaxf(mx, score[j]);
  float w[KNN]; float sum = 0.0f;
#pragma unroll
  for (int j = 0; j < KNN; ++j) { w[j] = expf(score[j] - mx); sum += w[j]; }
#pragma unroll
  for (int j = 0; j < KNN; ++j) w[j] = w[j] / sum;

  float a0 = 0.0f, a1 = 0.0f;
#pragma unroll
  for (int j = 0; j < KNN; ++j) {
    const size_t vrow = (size_t)(base + ni_[j]) * C_DIM;
    a0 = fmaf(w[j], v[vrow + lane], a0);
    a1 = fmaf(w[j], v[vrow + lane + 64], a1);
  }
  // agg aliases q's storage: safe, each q row is read only by its own wave
  agg[qrow + lane] = a0;
  agg[qrow + lane + 64] = a1;
}

// ---------------------------------------------------------------------------
extern "C" void kernel_launch(void* const* d_in, const int* in_sizes, int n_in,
                              void* d_out, int out_size, void* d_ws, size_t ws_size,
                              hipStream_t stream) {
  const float* feats  = (const float*)d_in[0];
  const float* coords = (const float*)d_in[1];
  const float* Wq     = (const float*)d_in[2];
  const float* Wk     = (const float*)d_in[3];
  const float* Wv     = (const float*)d_in[4];
  const float* Wo     = (const float*)d_in[5];
  const float* lg     = (const float*)d_in[6];
  float* out = (float*)d_out;

  float* ws = (float*)d_ws;
  const size_t ROWS = (size_t)M_TOTAL * C_DIM;   // 2,097,152 floats
  float*  q   = ws;                               // 8 MB
  float*  k   = ws + ROWS;                        // 8 MB
  float*  v   = ws + 2 * ROWS;                    // 8 MB
  float4* c4  = (float4*)(ws + 3 * ROWS);         // 256 KB, 16B-aligned
  float*  WTq = ws + 3 * ROWS + 4 * (size_t)M_TOTAL;
  float*  WTk = WTq + C_DIM * C_DIM;
  float*  WTv = WTk + C_DIM * C_DIM;
  float*  WTo = WTv + C_DIM * C_DIM;              // total ws use: ~24.8 MB
  float*  agg = q;                                // reuse q's buffer

  prep_coords<<<M_TOTAL / 256, 256, 0, stream>>>(coords, c4);
  transpose_w<<<256, 256, 0, stream>>>(Wq, Wk, Wv, Wo, WTq, WTk, WTv, WTo);
  gemm_qkv<<<M_TOTAL / 64, 256, 0, stream>>>(feats, WTq, WTk, WTv, q, k, v);
  knn_attn<<<M_TOTAL / 4, 256, 0, stream>>>(c4, q, k, v, lg, agg);
  gemm_xwt<<<M_TOTAL / 64, 256, 0, stream>>>(agg, WTo, out);
}